// Round 4
// baseline (190.060 us; speedup 1.0000x reference)
//
#include <hip/hip_runtime.h>
#include <float.h>
#include <math.h>

// ---------------------------------------------------------------------------
// DRR via Siddon ray casting.  NX=NY=NZ=192, H=W=192, SDR=300, DELX=DELY=2,
// SPACING=1, BAM=1, B=2, N_SUB=18432.
// Pipeline: memsets -> reduce -> scatter_mark -> count/scan/emit (parallel
// tile-ordered compact) -> ray (exact per-step midpoint voxel pick; cheap
// reciprocal-mul alpha updates; 8 alpha-chunks per ray).
// ---------------------------------------------------------------------------

#define NDIM   192
#define HW     (NDIM * NDIM)          // 36864
#define NSUB   (HW / 2)               // 18432
#define NTILE  576                    // 8x8 detector tiles
#define NBATCH 2
#define NCHUNK 8
#define NVOX   (NDIM * NDIM * NDIM)   // 7077888
#define SDRF   300.0f
#define RBLK   1728                   // reduce blocks: 1728*256*4 f4 == NVOX/4

// ws layout (bytes):
//   [0]  u32 enc_softmin (atomicMin, init 0xFFFFFFFF)
//   [4]  u32 enc_rmin    (atomicMin, init 0xFFFFFFFF)
//   [8]  u32 enc_rmax    (atomicMax, init 0)
//   [12] pad
//   [16 .. 16+HW)                      mark bytes
//   [16+HW .. +4*NSUB)                 list (tile-ordered selected pixels)
//   [.. +4*NTILE)                      per-tile counts
//   [.. +4*NTILE)                      per-tile offsets
#define WS_MARK_OFF 16
#define WS_LIST_OFF (16 + HW)
#define WS_CNT_OFF  (WS_LIST_OFF + 4 * NSUB)
#define WS_OFF_OFF  (WS_CNT_OFF + 4 * NTILE)

__device__ __forceinline__ unsigned int encf(float f) {
    unsigned int u = __float_as_uint(f);
    return (u & 0x80000000u) ? ~u : (u | 0x80000000u);
}
__device__ __forceinline__ float decf(unsigned int u) {
    return __uint_as_float((u & 0x80000000u) ? (u ^ 0x80000000u) : ~u);
}

// --------------------------- reduction kernel ------------------------------
// soft_min over (-800, 350]; rmin/rmax over v > -800 (BAM==1 -> identity).
__global__ __launch_bounds__(256) void reduce_kernel(
    const float* __restrict__ vol, unsigned int* __restrict__ ws) {
    const int tid = blockIdx.x * 256 + threadIdx.x;
    const float4* __restrict__ v4 = (const float4*)vol;
    const int S = RBLK * 256;         // 442368

    float4 r0 = v4[tid + 0 * S];
    float4 r1 = v4[tid + 1 * S];
    float4 r2 = v4[tid + 2 * S];
    float4 r3 = v4[tid + 3 * S];

    float smin = FLT_MAX, rmin = FLT_MAX, rmax = -FLT_MAX;
    float4 rr[4] = {r0, r1, r2, r3};
#pragma unroll
    for (int k = 0; k < 4; ++k) {
        float xs[4] = {rr[k].x, rr[k].y, rr[k].z, rr[k].w};
#pragma unroll
        for (int j = 0; j < 4; ++j) {
            float x = xs[j];
            bool in = (x > -800.0f);
            rmin = fminf(rmin, in ? x : FLT_MAX);
            rmax = fmaxf(rmax, in ? x : -FLT_MAX);
            smin = fminf(smin, (in && x <= 350.0f) ? x : FLT_MAX);
        }
    }
#pragma unroll
    for (int off = 32; off > 0; off >>= 1) {
        smin = fminf(smin, __shfl_down(smin, off));
        rmin = fminf(rmin, __shfl_down(rmin, off));
        rmax = fmaxf(rmax, __shfl_down(rmax, off));
    }
    __shared__ float sm[4], rm[4], rx[4];
    int w = threadIdx.x >> 6;
    if ((threadIdx.x & 63) == 0) { sm[w] = smin; rm[w] = rmin; rx[w] = rmax; }
    __syncthreads();
    if (threadIdx.x == 0) {
        float a = fminf(fminf(sm[0], sm[1]), fminf(sm[2], sm[3]));
        float b = fminf(fminf(rm[0], rm[1]), fminf(rm[2], rm[3]));
        float c = fmaxf(fmaxf(rx[0], rx[1]), fmaxf(rx[2], rx[3]));
        atomicMin(&ws[0], encf(a));
        atomicMin(&ws[1], encf(b));
        atomicMax(&ws[2], encf(c));
    }
}

// --------------------------- mark ------------------------------------------
__global__ __launch_bounds__(256) void scatter_mark(
    const int* __restrict__ idx, unsigned char* __restrict__ mark) {
    int n = blockIdx.x * blockDim.x + threadIdx.x;
    if (n < NSUB) mark[idx[n]] = 1;
}

// --------------------------- parallel tile-order compact -------------------
// key q = tile*64 + lane maps to pixel; 64 consecutive list entries then form
// ~two compact 8x8 detector patches -> coherent gather front in ray_kernel.
__device__ __forceinline__ int key_to_pixel(int tile, int lane) {
    int pi = (tile / 24) * 8 + (lane >> 3);
    int pj = (tile % 24) * 8 + (lane & 7);
    return pi * NDIM + pj;
}

__global__ __launch_bounds__(256) void count_kernel(
    const unsigned char* __restrict__ mark, int* __restrict__ counts) {
    int lane = threadIdx.x & 63;
    int tile = blockIdx.x * 4 + (threadIdx.x >> 6);
    int p = key_to_pixel(tile, lane);
    unsigned long long mask = __ballot(mark[p] != 0);
    if (lane == 0) counts[tile] = __popcll(mask);
}

__global__ __launch_bounds__(NTILE) void scan_kernel(
    const int* __restrict__ counts, int* __restrict__ offs) {
    __shared__ int s[NTILE];
    int t = threadIdx.x;
    int c = counts[t];
    s[t] = c;
    __syncthreads();
    for (int off = 1; off < NTILE; off <<= 1) {
        int v = s[t];
        int u = (t >= off) ? s[t - off] : 0;
        __syncthreads();
        s[t] = v + u;
        __syncthreads();
    }
    offs[t] = s[t] - c;               // exclusive prefix
}

__global__ __launch_bounds__(256) void emit_kernel(
    const unsigned char* __restrict__ mark, const int* __restrict__ offs,
    int* __restrict__ list) {
    int lane = threadIdx.x & 63;
    int tile = blockIdx.x * 4 + (threadIdx.x >> 6);
    int p = key_to_pixel(tile, lane);
    bool m = (mark[p] != 0);
    unsigned long long mask = __ballot(m);
    int rank = __popcll(mask & ((1ull << lane) - 1ull));
    if (m) list[offs[tile] + rank] = p;
}

// --------------------------- axis iterator init ----------------------------
// First plane index (walking toward increasing alpha) whose
// alpha = (i - s)/d is STRICTLY greater than a_lo.  Exact divides (once).
__device__ __forceinline__ void init_axis(float s, float d, float a_lo,
                                          int& i, int& st, float& na) {
    if (d > 0.0f) {
        st = 1;
        float f = s + a_lo * d;
        int ii = (int)floorf(f) + 1;
        ii = max(0, min(ii, NDIM + 1));
        while (ii <= NDIM && ((float)ii - s) / d <= a_lo) ++ii;
        while (ii > 0 && ((float)(ii - 1) - s) / d > a_lo) --ii;
        i  = ii;
        na = (ii <= NDIM) ? ((float)ii - s) / d : FLT_MAX;
    } else {
        st = -1;
        float f = s + a_lo * d;
        int ii = (int)ceilf(f) - 1;
        ii = max(-1, min(ii, NDIM));
        while (ii >= 0 && ((float)ii - s) / d <= a_lo) --ii;
        while (ii < NDIM && ((float)(ii + 1) - s) / d > a_lo) ++ii;
        i  = ii;
        na = (ii >= 0) ? ((float)ii - s) / d : FLT_MAX;
    }
}

// --------------------------- ray kernel ------------------------------------
// Wave = 64 consecutive list entries (compact detector patches).
// grid = (NSUB/256, NCHUNK, NBATCH), block = 256 (4 waves).
// Per step: exact midpoint voxel pick (matches reference); alpha crossings
// recomputed from integer plane index via reciprocal-mul (no drift).
__global__ __launch_bounds__(256) void ray_kernel(
    const float* __restrict__ vol, const float* __restrict__ rot,
    const float* __restrict__ trans, const unsigned int* __restrict__ wsc,
    const int* __restrict__ list, float* __restrict__ out) {
    const int n = blockIdx.x * 256 + threadIdx.x;
    const int c = blockIdx.y;
    const int b = blockIdx.z;

    const int p  = list[n];
    const int pi = p / NDIM;
    const int pj = p % NDIM;

    // density normalization constants
    float smin = decf(wsc[0]);
    float rmin = decf(wsc[1]);
    float rmax = decf(wsc[2]);
    float dmin = fminf(smin, rmin);
    float dmax = fmaxf(smin, rmax);
    float scale = 1.0f / (dmax - dmin);

    // rotation R = Rz(r0) @ Ry(r1) @ Rx(r2)
    float rz = rot[b * 3 + 0], ry = rot[b * 3 + 1], rx = rot[b * 3 + 2];
    float cz = cosf(rz), sz = sinf(rz);
    float cy = cosf(ry), sy = sinf(ry);
    float cx = cosf(rx), sx = sinf(rx);
    float R00 = cz * cy;
    float R01 = cz * sy * sx - sz * cx;
    float R02 = sz * sx + cz * sy * cx;
    float R10 = sz * cy;
    float R11 = cz * cx + sz * sy * sx;
    float R12 = sz * sy * cx - cz * sx;
    float R20 = -sy;
    float R21 = cy * sx;
    float R22 = cy * cx;
    float tx = trans[b * 3 + 0] + 96.0f;
    float ty = trans[b * 3 + 1] + 96.0f;
    float tz = trans[b * 3 + 2] + 96.0f;

    float srcx = R02 * SDRF + tx;
    float srcy = R12 * SDRF + ty;
    float srcz = R22 * SDRF + tz;
    float gx = ((float)pj - 95.5f) * 2.0f;
    float gy = ((float)pi - 95.5f) * 2.0f;
    float tgx = R00 * gx + R01 * gy + R02 * (-SDRF) + tx;
    float tgy = R10 * gx + R11 * gy + R12 * (-SDRF) + ty;
    float tgz = R20 * gx + R21 * gy + R22 * (-SDRF) + tz;

    float sdx = tgx - srcx, sdy = tgy - srcy, sdz = tgz - srcz;
    float dsx = (sdx == 0.0f) ? 1e-9f : sdx;
    float dsy = (sdy == 0.0f) ? 1e-9f : sdy;
    float dsz = (sdz == 0.0f) ? 1e-9f : sdz;

    float af0 = (0.0f - srcx) / dsx, al0 = (192.0f - srcx) / dsx;
    float af1 = (0.0f - srcy) / dsy, al1 = (192.0f - srcy) / dsy;
    float af2 = (0.0f - srcz) / dsz, al2 = (192.0f - srcz) / dsz;
    float amin = fmaxf(fmaxf(fminf(af0, al0), fminf(af1, al1)), fminf(af2, al2));
    amin = fmaxf(amin, 0.0f);
    float amax = fminf(fminf(fmaxf(af0, al0), fmaxf(af1, al1)), fmaxf(af2, al2));
    amax = fminf(amax, 1.0f);
    amax = fmaxf(amax, amin);
    float ray_len = sqrtf(sdx * sdx + sdy * sdy + sdz * sdz);

    // alpha sub-interval of this chunk
    float span = amax - amin;
    float a_lo = amin + span * ((float)c / (float)NCHUNK);
    float a_hi = (c == NCHUNK - 1) ? amax
                                   : amin + span * ((float)(c + 1) / (float)NCHUNK);

    int i0, i1, i2, st0, st1, st2;
    float na0, na1, na2;
    init_axis(srcx, dsx, a_lo, i0, st0, na0);
    init_axis(srcy, dsy, a_lo, i1, st1, na1);
    init_axis(srcz, dsz, a_lo, i2, st2, na2);

    // reciprocals (IEEE divide once per thread) and float-index trackers
    float r0 = 1.0f / dsx, r1 = 1.0f / dsy, r2 = 1.0f / dsz;
    float fi0 = (float)i0, fi1 = (float)i1, fi2 = (float)i2;
    float fs0 = (float)st0, fs1 = (float)st1, fs2 = (float)st2;

    float cur = a_lo;
    float acc = 0.0f;                 // sum of step * raw_density
    while (true) {
        float an  = fminf(fminf(na0, na1), na2);
        bool fin  = !(an < a_hi);
        float a2  = fin ? a_hi : an;
        float mid = 0.5f * (cur + a2);
        float px = fmaf(mid, sdx, srcx);
        float py = fmaf(mid, sdy, srcy);
        float pz = fmaf(mid, sdz, srcz);
        // truncation == floor after the >=0 clamp (see reference clip)
        int ix = min(max((int)px, 0), NDIM - 1);
        int iy = min(max((int)py, 0), NDIM - 1);
        int iz = min(max((int)pz, 0), NDIM - 1);
        int addr = (NDIM - 1) * HW - ix * HW + iy * NDIM + iz;  // flip axis 0
        float v  = vol[addr];
        float dv = (v <= -800.0f) ? smin : v;
        acc = fmaf(a2 - cur, dv, acc);
        if (fin) break;
        cur = a2;
        bool c0 = (na0 == an), c1 = (na1 == an), c2 = (na2 == an);
        // recompute crossing alpha from integer index: no drift accumulation
        float nf0 = fi0 + fs0, nf1 = fi1 + fs1, nf2 = fi2 + fs2;
        float nn0 = (nf0 - srcx) * r0;
        float nn1 = (nf1 - srcy) * r1;
        float nn2 = (nf2 - srcz) * r2;
        fi0 = c0 ? nf0 : fi0;  na0 = c0 ? nn0 : na0;
        fi1 = c1 ? nf1 : fi1;  na1 = c1 ? nn1 : na1;
        fi2 = c2 ? nf2 : fi2;  na2 = c2 ? nn2 : na2;
    }
    // sum step*(dv - dmin)*scale == scale*(acc - dmin*(a_hi - a_lo))
    float res = (acc - dmin * (a_hi - a_lo)) * scale * ray_len;
    atomicAdd(&out[b * HW + p], res);
}

// --------------------------- launch ----------------------------------------
extern "C" void kernel_launch(void* const* d_in, const int* in_sizes, int n_in,
                              void* d_out, int out_size, void* d_ws,
                              size_t ws_size, hipStream_t stream) {
    const float* vol   = (const float*)d_in[0];
    const float* rot   = (const float*)d_in[1];
    const float* trans = (const float*)d_in[2];
    const int*   sidx  = (const int*)d_in[3];
    float* out = (float*)d_out;

    unsigned int*  wsu    = (unsigned int*)d_ws;
    unsigned char* mark   = (unsigned char*)d_ws + WS_MARK_OFF;
    int*           list   = (int*)((unsigned char*)d_ws + WS_LIST_OFF);
    int*           counts = (int*)((unsigned char*)d_ws + WS_CNT_OFF);
    int*           offs   = (int*)((unsigned char*)d_ws + WS_OFF_OFF);

    hipMemsetAsync(d_out, 0, (size_t)out_size * sizeof(float), stream);
    hipMemsetAsync(wsu, 0xFF, 8, stream);            // enc_softmin, enc_rmin
    hipMemsetAsync((unsigned char*)d_ws + 8, 0, 8 + HW, stream); // rmax, mark

    reduce_kernel<<<RBLK, 256, 0, stream>>>(vol, wsu);
    scatter_mark<<<NSUB / 256, 256, 0, stream>>>(sidx, mark);
    count_kernel<<<NTILE / 4, 256, 0, stream>>>(mark, counts);
    scan_kernel<<<1, NTILE, 0, stream>>>(counts, offs);
    emit_kernel<<<NTILE / 4, 256, 0, stream>>>(mark, offs, list);
    dim3 rgrid(NSUB / 256, NCHUNK, NBATCH);
    ray_kernel<<<rgrid, 256, 0, stream>>>(vol, rot, trans, wsu, list, out);
}

// Round 5
// 126.874 us; speedup vs baseline: 1.4980x; 1.4980x over previous
//
#include <hip/hip_runtime.h>
#include <float.h>
#include <math.h>

// ---------------------------------------------------------------------------
// DRR via Siddon ray casting.  NX=NY=NZ=192, H=W=192, SDR=300, DELX=DELY=2,
// SPACING=1, BAM=1, B=2, N_SUB=18432.
// Pipeline: memsets -> reduce (block partials, NO atomics) -> reduce_final
// (1 block) -> scatter_mark -> count/scan/emit (tile-ordered compact) ->
// ray (exact per-step midpoint voxel pick; reciprocal-mul alpha updates;
// 16 alpha-chunks per ray).
//
// Perf history: r1 reduce=146us / r4 reduce=64us were SAME-CACHE-LINE atomic
// serialization (~12ns/atomic x 12288 / 5184 atomics).  Two-stage reduction
// with plain stores eliminates that.
// ---------------------------------------------------------------------------

#define NDIM   192
#define HW     (NDIM * NDIM)          // 36864
#define NSUB   (HW / 2)               // 18432
#define NTILE  576                    // 8x8 detector tiles
#define NBATCH 2
#define NCHUNK 16
#define NVOX   (NDIM * NDIM * NDIM)   // 7077888
#define SDRF   300.0f
#define RBLK   1728                   // reduce blocks: 1728*256*4 f4 == NVOX/4

// ws layout (bytes):
//   [0..12)   final {smin, rmin, rmax} floats (written by reduce_final)
//   [16 .. 16+HW)              mark bytes
//   [16+HW .. +4*NSUB)         list (tile-ordered selected pixels)
//   [.. +4*NTILE)              per-tile counts
//   [.. +4*NTILE)              per-tile offsets
//   [.. +4*3*RBLK)             block partials: smin[RBLK], rmin[RBLK], rmax[RBLK]
#define WS_MARK_OFF 16
#define WS_LIST_OFF (16 + HW)
#define WS_CNT_OFF  (WS_LIST_OFF + 4 * NSUB)
#define WS_OFF_OFF  (WS_CNT_OFF + 4 * NTILE)
#define WS_PART_OFF (WS_OFF_OFF + 4 * NTILE)

// --------------------------- reduction stage 1 -----------------------------
// soft_min over (-800, 350]; rmin/rmax over v > -800 (BAM==1 -> identity).
// Each block stores 3 partials to DISTINCT slots (no atomics).
__global__ __launch_bounds__(256) void reduce_kernel(
    const float* __restrict__ vol, float* __restrict__ parts) {
    const int tid = blockIdx.x * 256 + threadIdx.x;
    const float4* __restrict__ v4 = (const float4*)vol;
    const int S = RBLK * 256;         // 442368

    float4 r0 = v4[tid + 0 * S];
    float4 r1 = v4[tid + 1 * S];
    float4 r2 = v4[tid + 2 * S];
    float4 r3 = v4[tid + 3 * S];

    float smin = FLT_MAX, rmin = FLT_MAX, rmax = -FLT_MAX;
    float4 rr[4] = {r0, r1, r2, r3};
#pragma unroll
    for (int k = 0; k < 4; ++k) {
        float xs[4] = {rr[k].x, rr[k].y, rr[k].z, rr[k].w};
#pragma unroll
        for (int j = 0; j < 4; ++j) {
            float x = xs[j];
            bool in = (x > -800.0f);
            rmin = fminf(rmin, in ? x : FLT_MAX);
            rmax = fmaxf(rmax, in ? x : -FLT_MAX);
            smin = fminf(smin, (in && x <= 350.0f) ? x : FLT_MAX);
        }
    }
#pragma unroll
    for (int off = 32; off > 0; off >>= 1) {
        smin = fminf(smin, __shfl_down(smin, off));
        rmin = fminf(rmin, __shfl_down(rmin, off));
        rmax = fmaxf(rmax, __shfl_down(rmax, off));
    }
    __shared__ float sm[4], rm[4], rx[4];
    int w = threadIdx.x >> 6;
    if ((threadIdx.x & 63) == 0) { sm[w] = smin; rm[w] = rmin; rx[w] = rmax; }
    __syncthreads();
    if (threadIdx.x == 0) {
        parts[blockIdx.x] =
            fminf(fminf(sm[0], sm[1]), fminf(sm[2], sm[3]));
        parts[RBLK + blockIdx.x] =
            fminf(fminf(rm[0], rm[1]), fminf(rm[2], rm[3]));
        parts[2 * RBLK + blockIdx.x] =
            fmaxf(fmaxf(rx[0], rx[1]), fmaxf(rx[2], rx[3]));
    }
}

// --------------------------- reduction stage 2 -----------------------------
__global__ __launch_bounds__(256) void reduce_final(
    const float* __restrict__ parts, float* __restrict__ ws) {
    float smin = FLT_MAX, rmin = FLT_MAX, rmax = -FLT_MAX;
    for (int i = threadIdx.x; i < RBLK; i += 256) {
        smin = fminf(smin, parts[i]);
        rmin = fminf(rmin, parts[RBLK + i]);
        rmax = fmaxf(rmax, parts[2 * RBLK + i]);
    }
#pragma unroll
    for (int off = 32; off > 0; off >>= 1) {
        smin = fminf(smin, __shfl_down(smin, off));
        rmin = fminf(rmin, __shfl_down(rmin, off));
        rmax = fmaxf(rmax, __shfl_down(rmax, off));
    }
    __shared__ float sm[4], rm[4], rx[4];
    int w = threadIdx.x >> 6;
    if ((threadIdx.x & 63) == 0) { sm[w] = smin; rm[w] = rmin; rx[w] = rmax; }
    __syncthreads();
    if (threadIdx.x == 0) {
        ws[0] = fminf(fminf(sm[0], sm[1]), fminf(sm[2], sm[3]));
        ws[1] = fminf(fminf(rm[0], rm[1]), fminf(rm[2], rm[3]));
        ws[2] = fmaxf(fmaxf(rx[0], rx[1]), fmaxf(rx[2], rx[3]));
    }
}

// --------------------------- mark ------------------------------------------
__global__ __launch_bounds__(256) void scatter_mark(
    const int* __restrict__ idx, unsigned char* __restrict__ mark) {
    int n = blockIdx.x * blockDim.x + threadIdx.x;
    if (n < NSUB) mark[idx[n]] = 1;
}

// --------------------------- parallel tile-order compact -------------------
// key q = tile*64 + lane maps to pixel; 64 consecutive list entries then form
// ~two compact 8x8 detector patches -> coherent gather front in ray_kernel.
__device__ __forceinline__ int key_to_pixel(int tile, int lane) {
    int pi = (tile / 24) * 8 + (lane >> 3);
    int pj = (tile % 24) * 8 + (lane & 7);
    return pi * NDIM + pj;
}

__global__ __launch_bounds__(256) void count_kernel(
    const unsigned char* __restrict__ mark, int* __restrict__ counts) {
    int lane = threadIdx.x & 63;
    int tile = blockIdx.x * 4 + (threadIdx.x >> 6);
    int p = key_to_pixel(tile, lane);
    unsigned long long mask = __ballot(mark[p] != 0);
    if (lane == 0) counts[tile] = __popcll(mask);
}

__global__ __launch_bounds__(NTILE) void scan_kernel(
    const int* __restrict__ counts, int* __restrict__ offs) {
    __shared__ int s[NTILE];
    int t = threadIdx.x;
    int c = counts[t];
    s[t] = c;
    __syncthreads();
    for (int off = 1; off < NTILE; off <<= 1) {
        int v = s[t];
        int u = (t >= off) ? s[t - off] : 0;
        __syncthreads();
        s[t] = v + u;
        __syncthreads();
    }
    offs[t] = s[t] - c;               // exclusive prefix
}

__global__ __launch_bounds__(256) void emit_kernel(
    const unsigned char* __restrict__ mark, const int* __restrict__ offs,
    int* __restrict__ list) {
    int lane = threadIdx.x & 63;
    int tile = blockIdx.x * 4 + (threadIdx.x >> 6);
    int p = key_to_pixel(tile, lane);
    bool m = (mark[p] != 0);
    unsigned long long mask = __ballot(m);
    int rank = __popcll(mask & ((1ull << lane) - 1ull));
    if (m) list[offs[tile] + rank] = p;
}

// --------------------------- axis iterator init ----------------------------
// First plane index (walking toward increasing alpha) whose
// alpha = (i - s)/d is STRICTLY greater than a_lo.  Exact divides (once).
__device__ __forceinline__ void init_axis(float s, float d, float a_lo,
                                          int& i, int& st, float& na) {
    if (d > 0.0f) {
        st = 1;
        float f = s + a_lo * d;
        int ii = (int)floorf(f) + 1;
        ii = max(0, min(ii, NDIM + 1));
        while (ii <= NDIM && ((float)ii - s) / d <= a_lo) ++ii;
        while (ii > 0 && ((float)(ii - 1) - s) / d > a_lo) --ii;
        i  = ii;
        na = (ii <= NDIM) ? ((float)ii - s) / d : FLT_MAX;
    } else {
        st = -1;
        float f = s + a_lo * d;
        int ii = (int)ceilf(f) - 1;
        ii = max(-1, min(ii, NDIM));
        while (ii >= 0 && ((float)ii - s) / d <= a_lo) --ii;
        while (ii < NDIM && ((float)(ii + 1) - s) / d > a_lo) ++ii;
        i  = ii;
        na = (ii >= 0) ? ((float)ii - s) / d : FLT_MAX;
    }
}

// --------------------------- ray kernel ------------------------------------
// Wave = 64 consecutive list entries (compact detector patches).
// grid = (NSUB/256, NCHUNK, NBATCH), block = 256 (4 waves).
// Per step: exact midpoint voxel pick (matches reference); alpha crossings
// recomputed from integer plane index via reciprocal-mul (no drift).
__global__ __launch_bounds__(256) void ray_kernel(
    const float* __restrict__ vol, const float* __restrict__ rot,
    const float* __restrict__ trans, const float* __restrict__ wsc,
    const int* __restrict__ list, float* __restrict__ out) {
    const int n = blockIdx.x * 256 + threadIdx.x;
    const int c = blockIdx.y;
    const int b = blockIdx.z;

    const int p  = list[n];
    const int pi = p / NDIM;
    const int pj = p % NDIM;

    // density normalization constants
    float smin = wsc[0];
    float rmin = wsc[1];
    float rmax = wsc[2];
    float dmin = fminf(smin, rmin);
    float dmax = fmaxf(smin, rmax);
    float scale = 1.0f / (dmax - dmin);

    // rotation R = Rz(r0) @ Ry(r1) @ Rx(r2)
    float rz = rot[b * 3 + 0], ry = rot[b * 3 + 1], rx = rot[b * 3 + 2];
    float cz = cosf(rz), sz = sinf(rz);
    float cy = cosf(ry), sy = sinf(ry);
    float cx = cosf(rx), sx = sinf(rx);
    float R00 = cz * cy;
    float R01 = cz * sy * sx - sz * cx;
    float R02 = sz * sx + cz * sy * cx;
    float R10 = sz * cy;
    float R11 = cz * cx + sz * sy * sx;
    float R12 = sz * sy * cx - cz * sx;
    float R20 = -sy;
    float R21 = cy * sx;
    float R22 = cy * cx;
    float tx = trans[b * 3 + 0] + 96.0f;
    float ty = trans[b * 3 + 1] + 96.0f;
    float tz = trans[b * 3 + 2] + 96.0f;

    float srcx = R02 * SDRF + tx;
    float srcy = R12 * SDRF + ty;
    float srcz = R22 * SDRF + tz;
    float gx = ((float)pj - 95.5f) * 2.0f;
    float gy = ((float)pi - 95.5f) * 2.0f;
    float tgx = R00 * gx + R01 * gy + R02 * (-SDRF) + tx;
    float tgy = R10 * gx + R11 * gy + R12 * (-SDRF) + ty;
    float tgz = R20 * gx + R21 * gy + R22 * (-SDRF) + tz;

    float sdx = tgx - srcx, sdy = tgy - srcy, sdz = tgz - srcz;
    float dsx = (sdx == 0.0f) ? 1e-9f : sdx;
    float dsy = (sdy == 0.0f) ? 1e-9f : sdy;
    float dsz = (sdz == 0.0f) ? 1e-9f : sdz;

    float af0 = (0.0f - srcx) / dsx, al0 = (192.0f - srcx) / dsx;
    float af1 = (0.0f - srcy) / dsy, al1 = (192.0f - srcy) / dsy;
    float af2 = (0.0f - srcz) / dsz, al2 = (192.0f - srcz) / dsz;
    float amin = fmaxf(fmaxf(fminf(af0, al0), fminf(af1, al1)), fminf(af2, al2));
    amin = fmaxf(amin, 0.0f);
    float amax = fminf(fminf(fmaxf(af0, al0), fmaxf(af1, al1)), fmaxf(af2, al2));
    amax = fminf(amax, 1.0f);
    amax = fmaxf(amax, amin);
    float ray_len = sqrtf(sdx * sdx + sdy * sdy + sdz * sdz);

    // alpha sub-interval of this chunk
    float span = amax - amin;
    float a_lo = amin + span * ((float)c / (float)NCHUNK);
    float a_hi = (c == NCHUNK - 1) ? amax
                                   : amin + span * ((float)(c + 1) / (float)NCHUNK);

    int i0, i1, i2, st0, st1, st2;
    float na0, na1, na2;
    init_axis(srcx, dsx, a_lo, i0, st0, na0);
    init_axis(srcy, dsy, a_lo, i1, st1, na1);
    init_axis(srcz, dsz, a_lo, i2, st2, na2);

    // reciprocals (IEEE divide once per thread) and float-index trackers
    float r0 = 1.0f / dsx, r1 = 1.0f / dsy, r2 = 1.0f / dsz;
    float fi0 = (float)i0, fi1 = (float)i1, fi2 = (float)i2;
    float fs0 = (float)st0, fs1 = (float)st1, fs2 = (float)st2;

    float cur = a_lo;
    float acc = 0.0f;                 // sum of step * raw_density
    while (true) {
        float an  = fminf(fminf(na0, na1), na2);
        bool fin  = !(an < a_hi);
        float a2  = fin ? a_hi : an;
        float mid = 0.5f * (cur + a2);
        float px = fmaf(mid, sdx, srcx);
        float py = fmaf(mid, sdy, srcy);
        float pz = fmaf(mid, sdz, srcz);
        // truncation == floor after the >=0 clamp (see reference clip)
        int ix = min(max((int)px, 0), NDIM - 1);
        int iy = min(max((int)py, 0), NDIM - 1);
        int iz = min(max((int)pz, 0), NDIM - 1);
        int addr = (NDIM - 1) * HW - ix * HW + iy * NDIM + iz;  // flip axis 0
        float v  = vol[addr];
        float dv = (v <= -800.0f) ? smin : v;
        acc = fmaf(a2 - cur, dv, acc);
        if (fin) break;
        cur = a2;
        bool c0 = (na0 == an), c1 = (na1 == an), c2 = (na2 == an);
        // recompute crossing alpha from integer index: no drift accumulation
        float nf0 = fi0 + fs0, nf1 = fi1 + fs1, nf2 = fi2 + fs2;
        float nn0 = (nf0 - srcx) * r0;
        float nn1 = (nf1 - srcy) * r1;
        float nn2 = (nf2 - srcz) * r2;
        fi0 = c0 ? nf0 : fi0;  na0 = c0 ? nn0 : na0;
        fi1 = c1 ? nf1 : fi1;  na1 = c1 ? nn1 : na1;
        fi2 = c2 ? nf2 : fi2;  na2 = c2 ? nn2 : na2;
    }
    // sum step*(dv - dmin)*scale == scale*(acc - dmin*(a_hi - a_lo))
    float res = (acc - dmin * (a_hi - a_lo)) * scale * ray_len;
    atomicAdd(&out[b * HW + p], res);
}

// --------------------------- launch ----------------------------------------
extern "C" void kernel_launch(void* const* d_in, const int* in_sizes, int n_in,
                              void* d_out, int out_size, void* d_ws,
                              size_t ws_size, hipStream_t stream) {
    const float* vol   = (const float*)d_in[0];
    const float* rot   = (const float*)d_in[1];
    const float* trans = (const float*)d_in[2];
    const int*   sidx  = (const int*)d_in[3];
    float* out = (float*)d_out;

    float*         wsf    = (float*)d_ws;
    unsigned char* mark   = (unsigned char*)d_ws + WS_MARK_OFF;
    int*           list   = (int*)((unsigned char*)d_ws + WS_LIST_OFF);
    int*           counts = (int*)((unsigned char*)d_ws + WS_CNT_OFF);
    int*           offs   = (int*)((unsigned char*)d_ws + WS_OFF_OFF);
    float*         parts  = (float*)((unsigned char*)d_ws + WS_PART_OFF);

    hipMemsetAsync(d_out, 0, (size_t)out_size * sizeof(float), stream);
    hipMemsetAsync(mark, 0, HW, stream);

    reduce_kernel<<<RBLK, 256, 0, stream>>>(vol, parts);
    reduce_final<<<1, 256, 0, stream>>>(parts, wsf);
    scatter_mark<<<NSUB / 256, 256, 0, stream>>>(sidx, mark);
    count_kernel<<<NTILE / 4, 256, 0, stream>>>(mark, counts);
    scan_kernel<<<1, NTILE, 0, stream>>>(counts, offs);
    emit_kernel<<<NTILE / 4, 256, 0, stream>>>(mark, offs, list);
    dim3 rgrid(NSUB / 256, NCHUNK, NBATCH);
    ray_kernel<<<rgrid, 256, 0, stream>>>(vol, rot, trans, wsf, list, out);
}